// Round 1
// baseline (675.738 us; speedup 1.0000x reference)
//
#include <hip/hip_runtime.h>
#include <math.h>

#define BB 4
#define LQ 8400
#define EE 256
#define NH 8
#define NL 4
#define NP 4
#define HD 32
#define LVTOT 8500

// ---------------------------------------------------------------------------
// Generic 64x64 fp32 tiled GEMM: C[M x N] = A[M x 256] @ W[256 x N] + bias
// MODE 0: output permuted for v:  C0[((b*NH+h)*LVTOT+pix)*HD+d]
// MODE 1: N=384 split: cols 0..255 -> C0 (off, Wa), 256..383 -> C1 (aw, Wb)
// MODE 2: plain row-major C0[M x 256]
// ---------------------------------------------------------------------------
template<int MODE>
__global__ __launch_bounds__(256) void gemm_k(
    const float* __restrict__ A, int M,
    const float* __restrict__ Wa, const float* __restrict__ ba,
    const float* __restrict__ Wb, const float* __restrict__ bb,
    float* __restrict__ C0, float* __restrict__ C1)
{
    __shared__ float As[16][68];   // [k][m], +4 pad keeps 16B align & 2-way max
    __shared__ float Wsh[16][64];  // [k][n]

    const int tid = threadIdx.x;
    const int m0 = blockIdx.x * 64;
    const int n0 = blockIdx.y * 64;

    // A tile load: 64 rows x 16 k, each thread one float4
    const int ar = tid >> 2;          // row in tile
    const int ac = (tid & 3) << 2;    // k offset
    // W tile load: 16 k x 64 n, each thread one float4
    const int wr = tid >> 4;          // k row
    const int wc = (tid & 15) << 2;   // n offset
    // compute microtile
    const int tm = (tid >> 4) << 2;
    const int tn = (tid & 15) << 2;

    const int am = min(m0 + ar, M - 1);
    const float* aptr = A + (size_t)am * 256;

    const int ncol = n0 + wc;
    const float* wptr;
    int wstride;
    if (MODE == 1 && n0 >= 256) { wptr = Wb + (ncol - 256); wstride = 128; }
    else                        { wptr = Wa + ncol;         wstride = 256; }

    float acc[4][4];
    #pragma unroll
    for (int i = 0; i < 4; i++)
        #pragma unroll
        for (int j = 0; j < 4; j++) acc[i][j] = 0.f;

    for (int k0 = 0; k0 < 256; k0 += 16) {
        float4 av = *(const float4*)(aptr + k0 + ac);
        float4 wv = *(const float4*)(wptr + (size_t)(k0 + wr) * wstride);
        __syncthreads();
        As[ac + 0][ar] = av.x;
        As[ac + 1][ar] = av.y;
        As[ac + 2][ar] = av.z;
        As[ac + 3][ar] = av.w;
        *(float4*)&Wsh[wr][wc] = wv;
        __syncthreads();
        #pragma unroll
        for (int k = 0; k < 16; k++) {
            float4 a = *(const float4*)&As[k][tm];
            float4 w = *(const float4*)&Wsh[k][tn];
            float aa[4] = {a.x, a.y, a.z, a.w};
            float ww[4] = {w.x, w.y, w.z, w.w};
            #pragma unroll
            for (int i = 0; i < 4; i++)
                #pragma unroll
                for (int j = 0; j < 4; j++)
                    acc[i][j] = fmaf(aa[i], ww[j], acc[i][j]);
        }
    }

    #pragma unroll
    for (int i = 0; i < 4; i++) {
        int r = m0 + tm + i;
        if (r >= M) break;
        if (MODE == 0) {
            int bidx = r / LVTOT;
            int pix  = r - bidx * LVTOT;
            #pragma unroll
            for (int j = 0; j < 4; j++) {
                int c = n0 + tn + j;
                int h = c >> 5, d = c & 31;
                C0[(((size_t)(bidx * NH + h)) * LVTOT + pix) * HD + d] = acc[i][j] + ba[c];
            }
        } else if (MODE == 1) {
            if (n0 < 256) {
                #pragma unroll
                for (int j = 0; j < 4; j++) {
                    int c = n0 + tn + j;
                    C0[(size_t)r * 256 + c] = acc[i][j] + ba[c];
                }
            } else {
                #pragma unroll
                for (int j = 0; j < 4; j++) {
                    int c = n0 + tn + j - 256;
                    C1[(size_t)r * 128 + c] = acc[i][j] + bb[c];
                }
            }
        } else {
            #pragma unroll
            for (int j = 0; j < 4; j++) {
                int c = n0 + tn + j;
                C0[(size_t)r * 256 + c] = acc[i][j] + ba[c];
            }
        }
    }
}

// ---------------------------------------------------------------------------
// Sampling: one block per (b,q); 256 threads = 8 heads x 32 dims.
// vperm layout: [b][h][pix][d], 32 dims contiguous -> coalesced 128B gathers.
// ---------------------------------------------------------------------------
__global__ __launch_bounds__(256) void msda_sample(
    const float* __restrict__ vperm, const float* __restrict__ off,
    const float* __restrict__ awl, const float* __restrict__ refp,
    float* __restrict__ sampled)
{
    const int bq = blockIdx.x;             // 0 .. B*LQ-1
    const int b  = bq / LQ;
    const int tid = threadIdx.x;
    const int h = tid >> 5, d = tid & 31;

    __shared__ float s_off[256];
    __shared__ float s_aw[128];
    __shared__ float s_ref[8];

    s_off[tid] = off[(size_t)bq * 256 + tid];
    if (tid < 128) s_aw[tid] = awl[(size_t)bq * 128 + tid];
    if (tid < 8)   s_ref[tid] = refp[(size_t)bq * 8 + tid];
    __syncthreads();

    // softmax over 16 logits for this head (redundant per-lane, LDS-cached)
    float mx = -INFINITY;
    #pragma unroll
    for (int i = 0; i < 16; i++) mx = fmaxf(mx, s_aw[h * 16 + i]);
    float w[16];
    float sum = 0.f;
    #pragma unroll
    for (int i = 0; i < 16; i++) { w[i] = __expf(s_aw[h * 16 + i] - mx); sum += w[i]; }
    const float inv = 1.0f / sum;

    const int   Hs[4]   = {80, 40, 20, 10};
    const int   Wls[4]  = {80, 40, 20, 10};
    const int   base[4] = {0, 6400, 8000, 8400};

    const float* vp = vperm + ((size_t)(b * NH + h)) * LVTOT * HD + d;
    float acc = 0.f;

    #pragma unroll
    for (int l = 0; l < NL; l++) {
        const int Hl = Hs[l], Wl = Wls[l];
        const float rx = s_ref[l * 2 + 0];
        const float ry = s_ref[l * 2 + 1];
        #pragma unroll
        for (int p = 0; p < NP; p++) {
            float ox = s_off[h * 32 + l * 8 + p * 2 + 0];
            float oy = s_off[h * 32 + l * 8 + p * 2 + 1];
            float locx = rx + ox / (float)Wl;
            float locy = ry + oy / (float)Hl;
            float x = locx * (float)Wl - 0.5f;
            float y = locy * (float)Hl - 0.5f;
            float x0f = floorf(x), y0f = floorf(y);
            float wx = x - x0f, wy = y - y0f;
            int x0 = (int)x0f, y0 = (int)y0f;
            float aw  = w[l * 4 + p] * inv;
            float w00 = (1.f - wx) * (1.f - wy) * aw;
            float w01 = wx * (1.f - wy) * aw;
            float w10 = (1.f - wx) * wy * aw;
            float w11 = wx * wy * aw;
            bool vx0 = (x0 >= 0) && (x0 < Wl);
            bool vx1 = (x0 + 1 >= 0) && (x0 + 1 < Wl);
            if (y0 >= 0 && y0 < Hl) {
                const float* row = vp + (size_t)(base[l] + y0 * Wl) * HD;
                if (vx0) acc += w00 * row[(size_t)x0 * HD];
                if (vx1) acc += w01 * row[(size_t)(x0 + 1) * HD];
            }
            if (y0 + 1 >= 0 && y0 + 1 < Hl) {
                const float* row = vp + (size_t)(base[l] + (y0 + 1) * Wl) * HD;
                if (vx0) acc += w10 * row[(size_t)x0 * HD];
                if (vx1) acc += w11 * row[(size_t)(x0 + 1) * HD];
            }
        }
    }
    sampled[(size_t)bq * 256 + tid] = acc;
}

extern "C" void kernel_launch(void* const* d_in, const int* in_sizes, int n_in,
                              void* d_out, int out_size, void* d_ws, size_t ws_size,
                              hipStream_t stream) {
    const float* query = (const float*)d_in[0];
    const float* refp  = (const float*)d_in[1];
    const float* value = (const float*)d_in[2];
    // d_in[3] spatial_shapes: compile-time constants
    const float* Wv    = (const float*)d_in[4];
    const float* bv    = (const float*)d_in[5];
    const float* Woff  = (const float*)d_in[6];
    const float* boff  = (const float*)d_in[7];
    const float* Wattn = (const float*)d_in[8];
    const float* battn = (const float*)d_in[9];
    const float* Wo    = (const float*)d_in[10];
    const float* bo    = (const float*)d_in[11];
    float* out = (float*)d_out;

    float* ws = (float*)d_ws;
    float* vperm   = ws;                                    // 4*8*8500*32 = 8,704,000
    float* off     = vperm + (size_t)BB * NH * LVTOT * HD;  // 33600*256  = 8,601,600
    float* awl     = off + (size_t)BB * LQ * 256;           // 33600*128  = 4,300,800
    float* sampled = awl + (size_t)BB * LQ * 128;           // 33600*256  = 8,601,600

    const int M1 = BB * LVTOT;  // 34000
    const int M2 = BB * LQ;     // 33600

    dim3 g1((M1 + 63) / 64, 256 / 64);
    gemm_k<0><<<g1, 256, 0, stream>>>(value, M1, Wv, bv, nullptr, nullptr, vperm, nullptr);

    dim3 g2(M2 / 64, 384 / 64);
    gemm_k<1><<<g2, 256, 0, stream>>>(query, M2, Woff, boff, Wattn, battn, off, awl);

    msda_sample<<<dim3(BB * LQ), 256, 0, stream>>>(vperm, off, awl, refp, sampled);

    dim3 g3(M2 / 64, 256 / 64);
    gemm_k<2><<<g3, 256, 0, stream>>>(sampled, M2, Wo, bo, nullptr, nullptr, out, nullptr);
}

// Round 2
// 432.247 us; speedup vs baseline: 1.5633x; 1.5633x over previous
//
#include <hip/hip_runtime.h>
#include <math.h>

#define BB 4
#define LQ 8400
#define EE 256
#define NH 8
#define NL 4
#define NP 4
#define HD 32
#define LVTOT 8500

// ---------------------------------------------------------------------------
// Generic 64x64 fp32 tiled GEMM: C[M x N] = A[M x 256] @ W[256 x N] + bias
// MODE 0: output permuted for v:  C0[((b*NH+h)*LVTOT+pix)*HD+d]
// MODE 1: N=384 split: cols 0..255 -> C0 (off, Wa), 256..383 -> C1 (aw, Wb)
// MODE 2: plain row-major C0[M x 256]
// ---------------------------------------------------------------------------
template<int MODE>
__global__ __launch_bounds__(256) void gemm_k(
    const float* __restrict__ A, int M,
    const float* __restrict__ Wa, const float* __restrict__ ba,
    const float* __restrict__ Wb, const float* __restrict__ bb,
    float* __restrict__ C0, float* __restrict__ C1)
{
    __shared__ float As[16][68];   // [k][m], +4 pad keeps 16B align & 2-way max
    __shared__ float Wsh[16][64];  // [k][n]

    const int tid = threadIdx.x;
    const int m0 = blockIdx.x * 64;
    const int n0 = blockIdx.y * 64;

    const int ar = tid >> 2;          // row in tile
    const int ac = (tid & 3) << 2;    // k offset
    const int wr = tid >> 4;          // k row
    const int wc = (tid & 15) << 2;   // n offset
    const int tm = (tid >> 4) << 2;
    const int tn = (tid & 15) << 2;

    const int am = min(m0 + ar, M - 1);
    const float* aptr = A + (size_t)am * 256;

    const int ncol = n0 + wc;
    const float* wptr;
    int wstride;
    if (MODE == 1 && n0 >= 256) { wptr = Wb + (ncol - 256); wstride = 128; }
    else                        { wptr = Wa + ncol;         wstride = 256; }

    float acc[4][4];
    #pragma unroll
    for (int i = 0; i < 4; i++)
        #pragma unroll
        for (int j = 0; j < 4; j++) acc[i][j] = 0.f;

    for (int k0 = 0; k0 < 256; k0 += 16) {
        float4 av = *(const float4*)(aptr + k0 + ac);
        float4 wv = *(const float4*)(wptr + (size_t)(k0 + wr) * wstride);
        __syncthreads();
        As[ac + 0][ar] = av.x;
        As[ac + 1][ar] = av.y;
        As[ac + 2][ar] = av.z;
        As[ac + 3][ar] = av.w;
        *(float4*)&Wsh[wr][wc] = wv;
        __syncthreads();
        #pragma unroll
        for (int k = 0; k < 16; k++) {
            float4 a = *(const float4*)&As[k][tm];
            float4 w = *(const float4*)&Wsh[k][tn];
            float aa[4] = {a.x, a.y, a.z, a.w};
            float ww[4] = {w.x, w.y, w.z, w.w};
            #pragma unroll
            for (int i = 0; i < 4; i++)
                #pragma unroll
                for (int j = 0; j < 4; j++)
                    acc[i][j] = fmaf(aa[i], ww[j], acc[i][j]);
        }
    }

    #pragma unroll
    for (int i = 0; i < 4; i++) {
        int r = m0 + tm + i;
        if (r >= M) break;
        if (MODE == 0) {
            int bidx = r / LVTOT;
            int pix  = r - bidx * LVTOT;
            #pragma unroll
            for (int j = 0; j < 4; j++) {
                int c = n0 + tn + j;
                int h = c >> 5, d = c & 31;
                C0[(((size_t)(bidx * NH + h)) * LVTOT + pix) * HD + d] = acc[i][j] + ba[c];
            }
        } else if (MODE == 1) {
            if (n0 < 256) {
                #pragma unroll
                for (int j = 0; j < 4; j++) {
                    int c = n0 + tn + j;
                    C0[(size_t)r * 256 + c] = acc[i][j] + ba[c];
                }
            } else {
                #pragma unroll
                for (int j = 0; j < 4; j++) {
                    int c = n0 + tn + j - 256;
                    C1[(size_t)r * 128 + c] = acc[i][j] + bb[c];
                }
            }
        } else {
            #pragma unroll
            for (int j = 0; j < 4; j++) {
                int c = n0 + tn + j;
                C0[(size_t)r * 256 + c] = acc[i][j] + ba[c];
            }
        }
    }
}

// ---------------------------------------------------------------------------
// Sampling v2: block = 4 queries. Phase 1: 32 threads do per-(q,h) softmax
// stats. Phase 2: 512 point-slots (q,h,l,p) precompute 4 clamped byte-offsets
// + 4 premultiplied weights into LDS (stride-17 per-head pad -> conflict-free
// b128 reads). Phase 3: 1 wave per query, 8 lanes per head, float4 per lane:
// pure ds_read_b128 + global_load_dwordx4 + FMA.
// ---------------------------------------------------------------------------
__global__ __launch_bounds__(256) void msda_sample(
    const float* __restrict__ vperm, const float* __restrict__ off,
    const float* __restrict__ awl, const float* __restrict__ refp,
    float* __restrict__ sampled)
{
    __shared__ float  s_off[1024];
    __shared__ float  s_aw[512];
    __shared__ float  s_ref[32];
    __shared__ float  s_mx[32], s_inv[32];
    __shared__ float4 s_wv[544];   // (q*8+h)*17 + (l*4+p)
    __shared__ int4   s_iv[544];   // byte offsets into vperm head-plane

    const int tid = threadIdx.x;
    const int bq0 = blockIdx.x * 4;

    *(float4*)&s_off[tid * 4] = *(const float4*)(off + (size_t)bq0 * 256 + tid * 4);
    if (tid < 128) *(float4*)&s_aw[tid * 4] = *(const float4*)(awl + (size_t)bq0 * 128 + tid * 4);
    if (tid < 32)  s_ref[tid] = refp[(size_t)bq0 * 8 + tid];
    __syncthreads();

    if (tid < 32) {   // q = tid>>3, h = tid&7: serial softmax stats over 16
        const float* lg = &s_aw[(tid >> 3) * 128 + (tid & 7) * 16];
        float mx = lg[0];
        #pragma unroll
        for (int i = 1; i < 16; i++) mx = fmaxf(mx, lg[i]);
        float sum = 0.f;
        #pragma unroll
        for (int i = 0; i < 16; i++) sum += __expf(lg[i] - mx);
        s_mx[tid] = mx;
        s_inv[tid] = 1.0f / sum;
    }
    __syncthreads();

    const int Hs[4]   = {80, 40, 20, 10};
    const int base[4] = {0, 6400, 8000, 8400};

    #pragma unroll
    for (int s = tid; s < 512; s += 256) {
        const int q = s >> 7;
        const int r = s & 127;
        const int h = r >> 4, l = (r >> 2) & 3, p = r & 3;
        const int Wl = Hs[l], Hl = Hs[l];
        float rx = s_ref[q * 8 + l * 2 + 0];
        float ry = s_ref[q * 8 + l * 2 + 1];
        float ox = s_off[q * 256 + h * 32 + l * 8 + p * 2 + 0];
        float oy = s_off[q * 256 + h * 32 + l * 8 + p * 2 + 1];
        float lgt = s_aw[q * 128 + h * 16 + l * 4 + p];
        float aw = __expf(lgt - s_mx[q * 8 + h]) * s_inv[q * 8 + h];
        // x = (rx + ox/Wl)*Wl - 0.5 = rx*Wl + ox - 0.5
        float x = rx * (float)Wl + ox - 0.5f;
        float y = ry * (float)Hl + oy - 0.5f;
        float x0f = floorf(x), y0f = floorf(y);
        float wx = x - x0f, wy = y - y0f;
        int x0 = (int)x0f, y0 = (int)y0f;
        bool vx0 = (x0 >= 0) & (x0 < Wl);
        bool vx1 = (x0 + 1 >= 0) & (x0 + 1 < Wl);
        bool vy0 = (y0 >= 0) & (y0 < Hl);
        bool vy1 = (y0 + 1 >= 0) & (y0 + 1 < Hl);
        int cx0 = min(max(x0, 0), Wl - 1);
        int cx1 = min(max(x0 + 1, 0), Wl - 1);
        int cy0 = min(max(y0, 0), Hl - 1);
        int cy1 = min(max(y0 + 1, 0), Hl - 1);
        float w00 = (vx0 && vy0) ? (1.f - wx) * (1.f - wy) * aw : 0.f;
        float w01 = (vx1 && vy0) ? wx * (1.f - wy) * aw : 0.f;
        float w10 = (vx0 && vy1) ? (1.f - wx) * wy * aw : 0.f;
        float w11 = (vx1 && vy1) ? wx * wy * aw : 0.f;
        const int rec = (q * 8 + h) * 17 + (l * 4 + p);
        s_wv[rec] = make_float4(w00, w01, w10, w11);
        s_iv[rec] = make_int4((base[l] + cy0 * Wl + cx0) << 7,
                              (base[l] + cy0 * Wl + cx1) << 7,
                              (base[l] + cy1 * Wl + cx0) << 7,
                              (base[l] + cy1 * Wl + cx1) << 7);
    }
    __syncthreads();

    const int q    = tid >> 6;         // wave id = query
    const int lane = tid & 63;
    const int h    = lane >> 3;
    const int d4   = (lane & 7) * 4;
    const int bq   = bq0 + q;
    const int b    = bq / LQ;
    const char* vb = (const char*)(vperm + ((size_t)(b * NH + h)) * LVTOT * HD + d4);

    float4 acc = make_float4(0.f, 0.f, 0.f, 0.f);
    #pragma unroll
    for (int pt = 0; pt < 16; pt++) {
        const int rec = (q * 8 + h) * 17 + pt;
        float4 w  = s_wv[rec];
        int4   iv = s_iv[rec];
        float4 v0 = *(const float4*)(vb + iv.x);
        float4 v1 = *(const float4*)(vb + iv.y);
        float4 v2 = *(const float4*)(vb + iv.z);
        float4 v3 = *(const float4*)(vb + iv.w);
        acc.x += w.x * v0.x + w.y * v1.x + w.z * v2.x + w.w * v3.x;
        acc.y += w.x * v0.y + w.y * v1.y + w.z * v2.y + w.w * v3.y;
        acc.z += w.x * v0.z + w.y * v1.z + w.z * v2.z + w.w * v3.z;
        acc.w += w.x * v0.w + w.y * v1.w + w.z * v2.w + w.w * v3.w;
    }
    *(float4*)(sampled + (size_t)bq * 256 + h * 32 + d4) = acc;
}

extern "C" void kernel_launch(void* const* d_in, const int* in_sizes, int n_in,
                              void* d_out, int out_size, void* d_ws, size_t ws_size,
                              hipStream_t stream) {
    const float* query = (const float*)d_in[0];
    const float* refp  = (const float*)d_in[1];
    const float* value = (const float*)d_in[2];
    const float* Wv    = (const float*)d_in[4];
    const float* bv    = (const float*)d_in[5];
    const float* Woff  = (const float*)d_in[6];
    const float* boff  = (const float*)d_in[7];
    const float* Wattn = (const float*)d_in[8];
    const float* battn = (const float*)d_in[9];
    const float* Wo    = (const float*)d_in[10];
    const float* bo    = (const float*)d_in[11];
    float* out = (float*)d_out;

    float* ws = (float*)d_ws;
    float* vperm   = ws;                                    // 4*8*8500*32
    float* off     = vperm + (size_t)BB * NH * LVTOT * HD;  // 33600*256
    float* awl     = off + (size_t)BB * LQ * 256;           // 33600*128
    float* sampled = awl + (size_t)BB * LQ * 128;           // 33600*256

    const int M1 = BB * LVTOT;  // 34000
    const int M2 = BB * LQ;     // 33600

    dim3 g1((M1 + 63) / 64, 256 / 64);
    gemm_k<0><<<g1, 256, 0, stream>>>(value, M1, Wv, bv, nullptr, nullptr, vperm, nullptr);

    dim3 g2(M2 / 64, 384 / 64);
    gemm_k<1><<<g2, 256, 0, stream>>>(query, M2, Woff, boff, Wattn, battn, off, awl);

    msda_sample<<<dim3(BB * LQ / 4), 256, 0, stream>>>(vperm, off, awl, refp, sampled);

    dim3 g3(M2 / 64, 256 / 64);
    gemm_k<2><<<g3, 256, 0, stream>>>(sampled, M2, Wo, bo, nullptr, nullptr, out, nullptr);
}

// Round 4
// 266.836 us; speedup vs baseline: 2.5324x; 1.6199x over previous
//
#include <hip/hip_runtime.h>
#include <math.h>

#define BB 4
#define LQ 8400
#define NH 8
#define LVTOT 8500
#define HD 32

typedef __attribute__((ext_vector_type(8))) short short8;
typedef __attribute__((ext_vector_type(4))) float f32x4;
typedef unsigned short ushort_t;

__device__ __forceinline__ ushort_t f2bf(float f) {
    union { float f; unsigned u; } v; v.f = f;
    unsigned r = v.u + 0x7fffu + ((v.u >> 16) & 1u);   // RNE
    return (ushort_t)(r >> 16);
}
__device__ __forceinline__ float bflo(unsigned u) {
    union { unsigned u; float f; } x; x.u = u << 16; return x.f;
}
__device__ __forceinline__ float bfhi(unsigned u) {
    union { unsigned u; float f; } x; x.u = u & 0xffff0000u; return x.f;
}

// ---------------------------------------------------------------------------
// fp32 -> bf16 cast, float4/ushort4 vectorized
// ---------------------------------------------------------------------------
__global__ __launch_bounds__(256) void cast_bf16(
    const float* __restrict__ src, ushort_t* __restrict__ dst, int n4)
{
    int i = blockIdx.x * 256 + threadIdx.x;
    if (i < n4) {
        float4 f = ((const float4*)src)[i];
        ushort4 o;
        o.x = f2bf(f.x); o.y = f2bf(f.y); o.z = f2bf(f.z); o.w = f2bf(f.w);
        ((ushort4*)dst)[i] = o;
    }
}

// ---------------------------------------------------------------------------
// Build BT (transposed bf16 weights), 896 rows x 256 k:
// rows 0..255 = Wv^T, 256..639 = [Woff|Wattn]^T, 640..895 = Wo^T
// ---------------------------------------------------------------------------
__global__ __launch_bounds__(256) void prep_weights(
    const float* __restrict__ Wv, const float* __restrict__ Woff,
    const float* __restrict__ Wattn, const float* __restrict__ Wo,
    ushort_t* __restrict__ BT)
{
    int idx = blockIdx.x * 256 + threadIdx.x;   // 896*256
    int r = idx >> 8, k = idx & 255;
    float v;
    if (r < 256) v = Wv[k * 256 + r];
    else if (r < 640) {
        int n = r - 256;
        v = (n < 256) ? Woff[k * 256 + n] : Wattn[k * 128 + (n - 256)];
    } else v = Wo[k * 256 + (r - 640)];
    BT[idx] = f2bf(v);
}

// ---------------------------------------------------------------------------
// bf16 MFMA GEMM: C[M x N] = A[M x 256](bf16) @ BT^T + bias, 128x128 tile,
// 4 waves (2x2 of 64x64), BK=64, XOR-swizzled LDS:
//   physical_kseg = logical_kseg ^ (row & 7)
// Staging: thread loads LOGICAL segment scol from global (coalesced), stores
// at PHYSICAL scol^(m&7). Fragment read of logical ksl at physical ksl^(m&7).
// MODE 0: C -> vperm bf16 [b][h][pix][d];  MODE 1: cols<256 -> off fp32,
// cols>=256 -> awl fp32;  MODE 2: plain fp32 [M][256].
// ---------------------------------------------------------------------------
template<int MODE>
__global__ __launch_bounds__(256, 2) void gemm_mfma(
    const ushort_t* __restrict__ A, int M,
    const ushort_t* __restrict__ BT,
    const float* __restrict__ bias0, const float* __restrict__ bias1,
    float* __restrict__ Cf, ushort_t* __restrict__ Ch, float* __restrict__ C1)
{
    __shared__ ushort_t Asl[128 * 64];
    __shared__ ushort_t Bsl[128 * 64];

    const int tid  = threadIdx.x;
    const int m0   = blockIdx.x * 128;
    const int n0   = blockIdx.y * 128;
    const int wave = tid >> 6, lane = tid & 63;
    const int wm   = (wave >> 1) * 64, wn = (wave & 1) * 64;
    const int quad = lane >> 4, mr = lane & 15;
    const int srow = tid >> 3;        // 0..31
    const int scol = tid & 7;         // logical k segment handled by this thread

    f32x4 acc[4][4];
    #pragma unroll
    for (int i = 0; i < 4; i++)
        #pragma unroll
        for (int j = 0; j < 4; j++) acc[i][j] = (f32x4){0.f, 0.f, 0.f, 0.f};

    for (int k0 = 0; k0 < 256; k0 += 64) {
        short8 ra[4], rb[4];
        #pragma unroll
        for (int i = 0; i < 4; i++) {
            int m = i * 32 + srow;
            int am = min(m0 + m, M - 1);
            ra[i] = *(const short8*)(A  + (size_t)am * 256 + k0 + scol * 8);
            int bn = n0 + m;
            rb[i] = *(const short8*)(BT + (size_t)bn * 256 + k0 + scol * 8);
        }
        __syncthreads();
        #pragma unroll
        for (int i = 0; i < 4; i++) {
            int m = i * 32 + srow;
            int pseg = scol ^ (m & 7);     // physical = logical ^ (row&7)
            *(short8*)&Asl[m * 64 + pseg * 8] = ra[i];
            *(short8*)&Bsl[m * 64 + pseg * 8] = rb[i];
        }
        __syncthreads();
        #pragma unroll
        for (int ks = 0; ks < 2; ks++) {
            short8 af[4], bf[4];
            const int ksl = ks * 4 + quad;     // logical k segment
            #pragma unroll
            for (int i = 0; i < 4; i++) {
                int m = wm + i * 16 + mr;
                af[i] = *(const short8*)&Asl[m * 64 + (ksl ^ (m & 7)) * 8];
                int n = wn + i * 16 + mr;
                bf[i] = *(const short8*)&Bsl[n * 64 + (ksl ^ (n & 7)) * 8];
            }
            #pragma unroll
            for (int i = 0; i < 4; i++)
                #pragma unroll
                for (int j = 0; j < 4; j++)
                    acc[i][j] = __builtin_amdgcn_mfma_f32_16x16x32_bf16(
                        af[i], bf[j], acc[i][j], 0, 0, 0);
        }
        __syncthreads();
    }

    #pragma unroll
    for (int i = 0; i < 4; i++) {
        const int rbase = m0 + wm + i * 16 + quad * 4;
        #pragma unroll
        for (int j = 0; j < 4; j++) {
            const int c = n0 + wn + j * 16 + mr;
            #pragma unroll
            for (int reg = 0; reg < 4; reg++) {
                int row = rbase + reg;
                if (row >= M) continue;
                float val = acc[i][j][reg];
                if (MODE == 0) {
                    float o = val + bias0[c];
                    int b = row / LVTOT, pix = row - b * LVTOT;
                    int h = c >> 5, d = c & 31;
                    Ch[(((size_t)(b * NH + h)) * LVTOT + pix) * HD + d] = f2bf(o);
                } else if (MODE == 1) {
                    if (c < 256) Cf[(size_t)row * 256 + c] = val + bias0[c];
                    else         C1[(size_t)row * 128 + (c - 256)] = val + bias1[c - 256];
                } else {
                    Cf[(size_t)row * 256 + c] = val + bias0[c];
                }
            }
        }
    }
}

// ---------------------------------------------------------------------------
// Sampler: block = 4 queries; precompute per-point weights/offsets in LDS,
// then 1 wave/query, 8 lanes/head, 4 bf16 dims per lane (uint2 gathers).
// ---------------------------------------------------------------------------
__global__ __launch_bounds__(256) void msda_sample(
    const ushort_t* __restrict__ vperm, const float* __restrict__ off,
    const float* __restrict__ awl, const float* __restrict__ refp,
    ushort_t* __restrict__ sampled)
{
    __shared__ float  s_off[1024];
    __shared__ float  s_aw[512];
    __shared__ float  s_ref[32];
    __shared__ float  s_mx[32], s_inv[32];
    __shared__ float4 s_wv[544];   // (q*8+h)*17 + (l*4+p)
    __shared__ int4   s_iv[544];   // byte offsets into vperm head-plane

    const int tid = threadIdx.x;
    const int bq0 = blockIdx.x * 4;

    *(float4*)&s_off[tid * 4] = *(const float4*)(off + (size_t)bq0 * 256 + tid * 4);
    if (tid < 128) *(float4*)&s_aw[tid * 4] = *(const float4*)(awl + (size_t)bq0 * 128 + tid * 4);
    if (tid < 32)  s_ref[tid] = refp[(size_t)bq0 * 8 + tid];
    __syncthreads();

    if (tid < 32) {
        const float* lg = &s_aw[(tid >> 3) * 128 + (tid & 7) * 16];
        float mx = lg[0];
        #pragma unroll
        for (int i = 1; i < 16; i++) mx = fmaxf(mx, lg[i]);
        float sum = 0.f;
        #pragma unroll
        for (int i = 0; i < 16; i++) sum += __expf(lg[i] - mx);
        s_mx[tid] = mx;
        s_inv[tid] = 1.0f / sum;
    }
    __syncthreads();

    const int Hs[4]   = {80, 40, 20, 10};
    const int base[4] = {0, 6400, 8000, 8400};

    #pragma unroll
    for (int s = tid; s < 512; s += 256) {
        const int q = s >> 7;
        const int r = s & 127;
        const int h = r >> 4, l = (r >> 2) & 3, p = r & 3;
        const int Wl = Hs[l], Hl = Hs[l];
        float rx = s_ref[q * 8 + l * 2 + 0];
        float ry = s_ref[q * 8 + l * 2 + 1];
        float ox = s_off[q * 256 + h * 32 + l * 8 + p * 2 + 0];
        float oy = s_off[q * 256 + h * 32 + l * 8 + p * 2 + 1];
        float lgt = s_aw[q * 128 + h * 16 + l * 4 + p];
        float aw = __expf(lgt - s_mx[q * 8 + h]) * s_inv[q * 8 + h];
        float x = rx * (float)Wl + ox - 0.5f;
        float y = ry * (float)Hl + oy - 0.5f;
        float x0f = floorf(x), y0f = floorf(y);
        float wx = x - x0f, wy = y - y0f;
        int x0 = (int)x0f, y0 = (int)y0f;
        bool vx0 = (x0 >= 0) & (x0 < Wl);
        bool vx1 = (x0 + 1 >= 0) & (x0 + 1 < Wl);
        bool vy0 = (y0 >= 0) & (y0 < Hl);
        bool vy1 = (y0 + 1 >= 0) & (y0 + 1 < Hl);
        int cx0 = min(max(x0, 0), Wl - 1);
        int cx1 = min(max(x0 + 1, 0), Wl - 1);
        int cy0 = min(max(y0, 0), Hl - 1);
        int cy1 = min(max(y0 + 1, 0), Hl - 1);
        float w00 = (vx0 && vy0) ? (1.f - wx) * (1.f - wy) * aw : 0.f;
        float w01 = (vx1 && vy0) ? wx * (1.f - wy) * aw : 0.f;
        float w10 = (vx0 && vy1) ? (1.f - wx) * wy * aw : 0.f;
        float w11 = (vx1 && vy1) ? wx * wy * aw : 0.f;
        const int rec = (q * 8 + h) * 17 + (l * 4 + p);
        s_wv[rec] = make_float4(w00, w01, w10, w11);
        s_iv[rec] = make_int4((base[l] + cy0 * Wl + cx0) << 6,
                              (base[l] + cy0 * Wl + cx1) << 6,
                              (base[l] + cy1 * Wl + cx0) << 6,
                              (base[l] + cy1 * Wl + cx1) << 6);
    }
    __syncthreads();

    const int q    = tid >> 6;
    const int lane = tid & 63;
    const int h    = lane >> 3;
    const int d4   = (lane & 7) * 4;
    const int bq   = bq0 + q;
    const int b    = bq / LQ;
    const char* vb = (const char*)(vperm + ((size_t)(b * NH + h)) * LVTOT * HD + d4);

    float4 acc = make_float4(0.f, 0.f, 0.f, 0.f);
    #pragma unroll
    for (int pt = 0; pt < 16; pt++) {
        const int rec = (q * 8 + h) * 17 + pt;
        float4 w  = s_wv[rec];
        int4   iv = s_iv[rec];
        uint2 v0 = *(const uint2*)(vb + iv.x);
        uint2 v1 = *(const uint2*)(vb + iv.y);
        uint2 v2 = *(const uint2*)(vb + iv.z);
        uint2 v3 = *(const uint2*)(vb + iv.w);
        acc.x += w.x * bflo(v0.x) + w.y * bflo(v1.x) + w.z * bflo(v2.x) + w.w * bflo(v3.x);
        acc.y += w.x * bfhi(v0.x) + w.y * bfhi(v1.x) + w.z * bfhi(v2.x) + w.w * bfhi(v3.x);
        acc.z += w.x * bflo(v0.y) + w.y * bflo(v1.y) + w.z * bflo(v2.y) + w.w * bflo(v3.y);
        acc.w += w.x * bfhi(v0.y) + w.y * bfhi(v1.y) + w.z * bfhi(v2.y) + w.w * bfhi(v3.y);
    }
    ushort4 o;
    o.x = f2bf(acc.x); o.y = f2bf(acc.y); o.z = f2bf(acc.z); o.w = f2bf(acc.w);
    *(ushort4*)(sampled + (size_t)bq * 256 + h * 32 + d4) = o;
}

extern "C" void kernel_launch(void* const* d_in, const int* in_sizes, int n_in,
                              void* d_out, int out_size, void* d_ws, size_t ws_size,
                              hipStream_t stream) {
    const float* query = (const float*)d_in[0];
    const float* refp  = (const float*)d_in[1];
    const float* value = (const float*)d_in[2];
    const float* Wv    = (const float*)d_in[4];
    const float* bv    = (const float*)d_in[5];
    const float* Woff  = (const float*)d_in[6];
    const float* boff  = (const float*)d_in[7];
    const float* Wattn = (const float*)d_in[8];
    const float* battn = (const float*)d_in[9];
    const float* Wo    = (const float*)d_in[10];
    const float* bo    = (const float*)d_in[11];
    float* out = (float*)d_out;

    float* ws = (float*)d_ws;
    float* off = ws;                               // 33600*256 fp32
    float* awl = off + (size_t)33600 * 256;        // 33600*128 fp32
    ushort_t* ub      = (ushort_t*)(awl + (size_t)33600 * 128);
    ushort_t* value_b = ub;                        // 8,704,000
    ushort_t* query_b = value_b + 8704000;         // 8,601,600 (aliased w/ sampled)
    ushort_t* vperm_b = query_b + 8601600;         // 8,704,000
    ushort_t* BT      = vperm_b + 8704000;         // 896*256
    ushort_t* sampled_b = query_b;                 // alias: query dead after GEMM2

    const int M1 = BB * LVTOT;  // 34000
    const int M2 = BB * LQ;     // 33600

    cast_bf16<<<dim3(8500), 256, 0, stream>>>(value, value_b, 8704000 / 4);
    cast_bf16<<<dim3(8400), 256, 0, stream>>>(query, query_b, 8601600 / 4);
    prep_weights<<<dim3(896), 256, 0, stream>>>(Wv, Woff, Wattn, Wo, BT);

    gemm_mfma<0><<<dim3(266, 2), 256, 0, stream>>>(
        value_b, M1, BT, bv, nullptr, nullptr, vperm_b, nullptr);
    gemm_mfma<1><<<dim3(263, 3), 256, 0, stream>>>(
        query_b, M2, BT + 65536, boff, battn, off, nullptr, awl);

    msda_sample<<<dim3(M2 / 4), 256, 0, stream>>>(vperm_b, off, awl, refp, sampled_b);

    gemm_mfma<2><<<dim3(263, 2), 256, 0, stream>>>(
        sampled_b, M2, BT + 65536 + 98304, bo, nullptr, out, nullptr, nullptr);
}